// Round 13
// baseline (123.666 us; speedup 1.0000x reference)
//
#include <hip/hip_runtime.h>
#include <hip/hip_bf16.h>
#include <math.h>

#define NB 512
#define NQ 30
#define ND 512
#define NE 128
#define NK 21
#define VOCAB 50000
#define REP 3   // instrumentation: x3 compute passes, scaled by 1/3

typedef __attribute__((ext_vector_type(4))) float f32x4;
typedef __attribute__((ext_vector_type(2))) float f32x2;
typedef __attribute__((ext_vector_type(8))) short short8;

#define AS1C(p) ((const __attribute__((address_space(1))) unsigned int*)(p))
#define AS3C(p) ((__attribute__((address_space(3))) unsigned int*)(p))

// normalized vocab table, bf16 (12.8 MB). Fully rewritten every launch (idempotent).
__device__ unsigned short g_norm[(size_t)VOCAB * NE];
// 256B of zeros for padding q-rows 30,31. Never written -> stays zero.
__device__ unsigned short g_zero[NE];

__device__ __forceinline__ unsigned short f2bf(float f) {
  unsigned int x = __builtin_bit_cast(unsigned int, f);
  x = (x + 0x7fffu + ((x >> 16) & 1u)) >> 16;   // RNE
  return (unsigned short)x;
}

// ---------------- kernel 1: normalize vocab to bf16 ----------------
__global__ __launch_bounds__(256) void norm_kernel(const float* __restrict__ emb) {
  const int t = threadIdx.x;
  const int row = blockIdx.x * 8 + (t >> 5);
  const int j = t & 31;
  const float* src = emb + (size_t)row * NE;
  float4 v = *(const float4*)(src + j * 4);
  float ssq = v.x * v.x + v.y * v.y + v.z * v.z + v.w * v.w;
  ssq += __shfl_xor(ssq, 1);
  ssq += __shfl_xor(ssq, 2);
  ssq += __shfl_xor(ssq, 4);
  ssq += __shfl_xor(ssq, 8);
  ssq += __shfl_xor(ssq, 16);
  const float sc = 1.0f / fmaxf(sqrtf(ssq), 1e-12f);
  ushort4 o;
  o.x = f2bf(v.x * sc); o.y = f2bf(v.y * sc);
  o.z = f2bf(v.z * sc); o.w = f2bf(v.w * sc);
  *(ushort4*)(g_norm + (size_t)row * NE + j * 4) = o;
}

// ---------------- kernel 2: fused KNRM, one block per b, 1024 threads ----------
// 16 waves; wave w: qt=w&1 (16 q cols), dgg=w>>1 (16 d rows/quarter).
// 32 waves/CU capacity (2 blocks x 16 waves) = 100% occupancy ceiling.
__global__ __launch_bounds__(1024, 8) void knrm_part(
    const int* __restrict__ query, const int* __restrict__ doc,
    const float* __restrict__ w1, const float* __restrict__ b1,
    const float* __restrict__ w2, const float* __restrict__ b2,
    const float* __restrict__ w3, const float* __restrict__ b3,
    float* __restrict__ out)
{
  extern __shared__ unsigned char smem_raw[];
  unsigned short* dtA   = (unsigned short*)smem_raw;    // [128][128] bf16, slot-swizzled
  unsigned short* dtB   = dtA + 128 * NE;               // [128][128]
  unsigned short* qtile = dtB + 128 * NE;               // [32][128]
  float*          Sex   = (float*)(qtile + 32 * NE);    // [32]

  const int t = threadIdx.x;
  const int b = blockIdx.x;
  const int wave = t >> 6, lane = t & 63;
  const int srow4 = lane >> 4, slot = lane & 15;
  const int lrow = lane & 15, lgrp = lane >> 4;
  const int qt = wave & 1, dgg = wave >> 1;   // 0..7

  // ---- stage qtile (once): waves 0-7, 4 rows each ----
  if (wave < 8) {
    const int qr = wave * 4 + srow4;
    const unsigned short* srcrow =
        (qr < NQ) ? (g_norm + (size_t)query[b * NQ + qr] * NE) : g_zero;
    __builtin_amdgcn_global_load_lds(AS1C(srcrow + ((slot ^ (qr & 7)) * 8)),
                                     AS3C(qtile + (wave * 4) * NE), 16, 0, 0);
  }
  if (t < 32) Sex[t] = 0.0f;
  __syncthreads();

  // ---- exact-match kernel (mu=1, sigma=0.001): integer ID equality ----
  if (t < ND) {
    const int did = doc[b * ND + t];
    const int* qp = query + b * NQ;   // uniform -> scalar loads
#pragma unroll 1
    for (int q = 0; q < NQ; ++q)
      if (did == qp[q]) atomicAdd(&Sex[q], 1.0f);   // block-local, +1.0 only
  }

  // recurrence constants (Cc*ln2 = -50 exactly)
  const float Cc = -72.13475204444817f;           // -50/ln2
  const float ACOEF = 14.426950408889634f;        // 10/ln2 : A = e^{10m}
  const float Rr = 0.36787944117144233f;          // e^-1
  const float Hc[5] = { 8103.083927575384f, 148.4131591025766f,
                        2.718281828459045f, 0.049787068367863944f,
                        0.0009118819655545162f }; // e^{-10*mu_k0 - 0.5}
  const float Bc[5] = { -137.05602888445152f, -79.34822724889299f,
                        -21.64042561333445f, 36.067376022224085f,
                        93.77517765778262f };     // -2*Cc*mu_k0
  const float Gc[5] = { -65.10161372011448f, -21.820762493445572f,
                        -1.6230319210000838f, -4.508422002778011f,
                        -30.47693273877935f };    // Cc*mu_k0^2

  f32x2 s2[20];
#pragma unroll
  for (int k = 0; k < 20; ++k) s2[k] = (f32x2){0.f, 0.f};

  const int qrow = qt * 16 + lrow;

#pragma unroll 1
  for (int rep = 0; rep < REP; ++rep) {
    // stage quarter 0 into dtA: each wave 8 rows = 2 ops
#pragma unroll
    for (int h = 0; h < 2; ++h) {
      const int r = wave * 8 + h * 4 + srow4;
      const int id = doc[b * ND + r];
      __builtin_amdgcn_global_load_lds(
          AS1C(g_norm + (size_t)id * NE + ((slot ^ (r & 7)) * 8)),
          AS3C(dtA + (wave * 8 + h * 4) * NE), 16, 0, 0);
    }
    __syncthreads();   // dtA ready

#pragma unroll 1
    for (int qq = 0; qq < 4; ++qq) {
      unsigned short* cur = (qq & 1) ? dtB : dtA;
      unsigned short* nxt = (qq & 1) ? dtA : dtB;
      if (qq < 3) {   // prefetch next quarter during compute
#pragma unroll
        for (int h = 0; h < 2; ++h) {
          const int r = wave * 8 + h * 4 + srow4;
          const int id = doc[b * ND + (qq + 1) * 128 + r];
          __builtin_amdgcn_global_load_lds(
              AS1C(g_norm + (size_t)id * NE + ((slot ^ (r & 7)) * 8)),
              AS3C(nxt + (wave * 8 + h * 4) * NE), 16, 0, 0);
        }
      }
      // ---- MFMA: 16 d-rows x 16 q for this wave ----
      f32x4 acc = (f32x4){0.f, 0.f, 0.f, 0.f};
      const int R = dgg * 16 + lrow;
#pragma unroll
      for (int ks = 0; ks < 4; ++ks) {
        const int qs = (ks * 4 + lgrp) ^ (qrow & 7);
        short8 bq = *(const short8*)(qtile + qrow * NE + qs * 8);
        const int as = (ks * 4 + lgrp) ^ (R & 7);
        short8 a = *(const short8*)(cur + R * NE + as * 8);
        acc = __builtin_amdgcn_mfma_f32_16x16x32_bf16(a, bq, acc, 0, 0, 0);
      }
      // ---- recurrence pooling: 2 element-pairs, f32x2 ----
#pragma unroll
      for (int h = 0; h < 2; ++h) {
        f32x2 m2 = { acc[2 * h], acc[2 * h + 1] };
        f32x2 Aarg = m2 * ACOEF;
        f32x2 A2 = { __builtin_amdgcn_exp2f(Aarg.x), __builtin_amdgcn_exp2f(Aarg.y) };
#pragma unroll
        for (int j = 0; j < 5; ++j) {
          f32x2 arg = m2 * (m2 * Cc + Bc[j]) + Gc[j];
          f32x2 E2 = { __builtin_amdgcn_exp2f(arg.x), __builtin_amdgcn_exp2f(arg.y) };
          f32x2 W2 = A2 * Hc[j];
          s2[4 * j]     += E2;
          E2 *= W2; W2 *= Rr;
          s2[4 * j + 1] += E2;
          E2 *= W2; W2 *= Rr;
          s2[4 * j + 2] += E2;
          E2 *= W2;
          s2[4 * j + 3] += E2;
        }
      }
      __syncthreads();   // drains prefetch; orders buffer reuse
    }
  }

  // ---- fold pairs (scale by 1/REP) + wave reduce ----
  const float invrep = 1.0f / (float)REP;
  float s[20];
#pragma unroll
  for (int k = 0; k < 20; ++k) {
    s[k] = (s2[k].x + s2[k].y) * invrep;
    s[k] += __shfl_xor(s[k], 16);
    s[k] += __shfl_xor(s[k], 32);
  }
  float* Sw  = (float*)dtA;      // [16 waves][16 lrow][20 k] = 20480 B (dtA dead)
  float* buf = Sw + 5120;        // [NQ*NK]
  float* km  = buf + 640;        // [21]
  float* h1  = km + 32;          // [10]
  float* h2  = h1 + 16;          // [5]
  if (lgrp == 0) {
#pragma unroll
    for (int k = 0; k < 20; ++k) Sw[(wave * 16 + lrow) * 20 + k] = s[k];
  }
  __syncthreads();

  // ---- block reduce + log1p (one (q,k) per thread) ----
  if (t < NQ * NK) {
    const int q = t / NK, k = t % NK;
    float v;
    if (k < 20) {
      const int w0 = q >> 4;
      v = 0.f;
#pragma unroll
      for (int g = 0; g < 8; ++g) v += Sw[((g * 2 + w0) * 16 + (q & 15)) * 20 + k];
    } else {
      v = Sex[q];
    }
    buf[t] = log1pf(v);
  }
  __syncthreads();

  // ---- fused MLP 21->10->5->1 ----
  if (t < NK) {
    float acc0 = 0.f;
#pragma unroll 1
    for (int q = 0; q < NQ; ++q) acc0 += buf[q * NK + t];
    km[t] = acc0;
  }
  __syncthreads();
  if (t < 10) {
    float a = b1[t];
#pragma unroll 1
    for (int k = 0; k < NK; ++k) a = fmaf(km[k], w1[k * 10 + t], a);
    h1[t] = fmaxf(a, 0.f);
  }
  __syncthreads();
  if (t < 5) {
    float a = b2[t];
#pragma unroll 1
    for (int k = 0; k < 10; ++k) a = fmaf(h1[k], w2[k * 5 + t], a);
    h2[t] = fmaxf(a, 0.f);
  }
  __syncthreads();
  if (t == 0) {
    float a = b3[0];
#pragma unroll 1
    for (int k = 0; k < 5; ++k) a = fmaf(h2[k], w3[k], a);
    out[b] = a;
  }
}

extern "C" void kernel_launch(void* const* d_in, const int* in_sizes, int n_in,
                              void* d_out, int out_size, void* d_ws, size_t ws_size,
                              hipStream_t stream) {
  const int*   query = (const int*)d_in[0];
  const int*   doc   = (const int*)d_in[1];
  const float* emb   = (const float*)d_in[2];
  const float* w1    = (const float*)d_in[3];
  const float* b1    = (const float*)d_in[4];
  const float* w2    = (const float*)d_in[5];
  const float* b2    = (const float*)d_in[6];
  const float* w3    = (const float*)d_in[7];
  const float* b3    = (const float*)d_in[8];
  float* out = (float*)d_out;

  const size_t sh = (size_t)128 * NE * 2 * 2   // dtA + dtB  65536
                  + (size_t)32 * NE * 2        // qtile       8192
                  + 32 * 4;                    // Sex          128  -> 73856
  hipFuncSetAttribute((const void*)knrm_part,
                      hipFuncAttributeMaxDynamicSharedMemorySize, (int)sh);

  norm_kernel<<<dim3(VOCAB / 8), dim3(256), 0, stream>>>(emb);
  knrm_part<<<dim3(NB), dim3(1024), sh, stream>>>(
      query, doc, w1, b1, w2, b2, w3, b3, out);
}

// Round 14
// 83.414 us; speedup vs baseline: 1.4826x; 1.4826x over previous
//
#include <hip/hip_runtime.h>
#include <hip/hip_bf16.h>
#include <math.h>

#define NB 512
#define NQ 30
#define ND 512
#define NE 128
#define NK 21
#define VOCAB 50000
#define REP 3   // instrumentation: x3 compute passes, scaled by 1/3

typedef __attribute__((ext_vector_type(4))) float f32x4;
typedef __attribute__((ext_vector_type(2))) float f32x2;
typedef __attribute__((ext_vector_type(8))) short short8;

#define AS1C(p) ((const __attribute__((address_space(1))) unsigned int*)(p))
#define AS3C(p) ((__attribute__((address_space(3))) unsigned int*)(p))

// normalized vocab table, bf16 (12.8 MB). Fully rewritten every launch (idempotent).
__device__ unsigned short g_norm[(size_t)VOCAB * NE];
// 256B of zeros for padding q-rows 30,31. Never written -> stays zero.
__device__ unsigned short g_zero[NE];

__device__ __forceinline__ unsigned short f2bf(float f) {
  unsigned int x = __builtin_bit_cast(unsigned int, f);
  x = (x + 0x7fffu + ((x >> 16) & 1u)) >> 16;   // RNE
  return (unsigned short)x;
}

// ---------------- kernel 1: normalize vocab to bf16 ----------------
__global__ __launch_bounds__(256) void norm_kernel(const float* __restrict__ emb) {
  const int t = threadIdx.x;
  const int row = blockIdx.x * 8 + (t >> 5);
  const int j = t & 31;
  const float* src = emb + (size_t)row * NE;
  float4 v = *(const float4*)(src + j * 4);
  float ssq = v.x * v.x + v.y * v.y + v.z * v.z + v.w * v.w;
  ssq += __shfl_xor(ssq, 1);
  ssq += __shfl_xor(ssq, 2);
  ssq += __shfl_xor(ssq, 4);
  ssq += __shfl_xor(ssq, 8);
  ssq += __shfl_xor(ssq, 16);
  const float sc = 1.0f / fmaxf(sqrtf(ssq), 1e-12f);
  ushort4 o;
  o.x = f2bf(v.x * sc); o.y = f2bf(v.y * sc);
  o.z = f2bf(v.z * sc); o.w = f2bf(v.w * sc);
  *(ushort4*)(g_norm + (size_t)row * NE + j * 4) = o;
}

// ---------------- kernel 2: fused KNRM, one block per b, 1024 threads ----------
// 16 waves; wave w: qt=w&1 (16 q cols), dgg=w>>1 (16 d rows/quarter).
// launch_bounds(1024,4): VGPR cap 128 (R13's (1024,8) cap=64 forced a spill:
// VGPR_Count=32, FETCH 3x, VALUBusy 29%). Residency: VGPR~56 -> 8 waves/SIMD;
// LDS 73856*2 fits -> 2 blocks/CU x 16 waves = 32 waves/CU.
__global__ __launch_bounds__(1024, 4) void knrm_part(
    const int* __restrict__ query, const int* __restrict__ doc,
    const float* __restrict__ w1, const float* __restrict__ b1,
    const float* __restrict__ w2, const float* __restrict__ b2,
    const float* __restrict__ w3, const float* __restrict__ b3,
    float* __restrict__ out)
{
  extern __shared__ unsigned char smem_raw[];
  unsigned short* dtA   = (unsigned short*)smem_raw;    // [128][128] bf16, slot-swizzled
  unsigned short* dtB   = dtA + 128 * NE;               // [128][128]
  unsigned short* qtile = dtB + 128 * NE;               // [32][128]
  float*          Sex   = (float*)(qtile + 32 * NE);    // [32]

  const int t = threadIdx.x;
  const int b = blockIdx.x;
  const int wave = t >> 6, lane = t & 63;
  const int srow4 = lane >> 4, slot = lane & 15;
  const int lrow = lane & 15, lgrp = lane >> 4;
  const int qt = wave & 1, dgg = wave >> 1;   // 0..7

  // ---- stage qtile (once): waves 0-7, 4 rows each ----
  if (wave < 8) {
    const int qr = wave * 4 + srow4;
    const unsigned short* srcrow =
        (qr < NQ) ? (g_norm + (size_t)query[b * NQ + qr] * NE) : g_zero;
    __builtin_amdgcn_global_load_lds(AS1C(srcrow + ((slot ^ (qr & 7)) * 8)),
                                     AS3C(qtile + (wave * 4) * NE), 16, 0, 0);
  }
  if (t < 32) Sex[t] = 0.0f;
  __syncthreads();

  // ---- exact-match kernel (mu=1, sigma=0.001): integer ID equality ----
  if (t < ND) {
    const int did = doc[b * ND + t];
    const int* qp = query + b * NQ;   // uniform -> scalar loads
#pragma unroll 1
    for (int q = 0; q < NQ; ++q)
      if (did == qp[q]) atomicAdd(&Sex[q], 1.0f);   // block-local, +1.0 only
  }

  // recurrence constants (Cc*ln2 = -50 exactly)
  const float Cc = -72.13475204444817f;           // -50/ln2
  const float ACOEF = 14.426950408889634f;        // 10/ln2 : A = e^{10m}
  const float Rr = 0.36787944117144233f;          // e^-1
  const float Hc[5] = { 8103.083927575384f, 148.4131591025766f,
                        2.718281828459045f, 0.049787068367863944f,
                        0.0009118819655545162f }; // e^{-10*mu_k0 - 0.5}
  const float Bc[5] = { -137.05602888445152f, -79.34822724889299f,
                        -21.64042561333445f, 36.067376022224085f,
                        93.77517765778262f };     // -2*Cc*mu_k0
  const float Gc[5] = { -65.10161372011448f, -21.820762493445572f,
                        -1.6230319210000838f, -4.508422002778011f,
                        -30.47693273877935f };    // Cc*mu_k0^2

  f32x2 s2[20];
#pragma unroll
  for (int k = 0; k < 20; ++k) s2[k] = (f32x2){0.f, 0.f};

  const int qrow = qt * 16 + lrow;

#pragma unroll 1
  for (int rep = 0; rep < REP; ++rep) {
    // stage quarter 0 into dtA: each wave 8 rows = 2 ops
#pragma unroll
    for (int h = 0; h < 2; ++h) {
      const int r = wave * 8 + h * 4 + srow4;
      const int id = doc[b * ND + r];
      __builtin_amdgcn_global_load_lds(
          AS1C(g_norm + (size_t)id * NE + ((slot ^ (r & 7)) * 8)),
          AS3C(dtA + (wave * 8 + h * 4) * NE), 16, 0, 0);
    }
    __syncthreads();   // dtA ready

#pragma unroll 1
    for (int qq = 0; qq < 4; ++qq) {
      unsigned short* cur = (qq & 1) ? dtB : dtA;
      unsigned short* nxt = (qq & 1) ? dtA : dtB;
      if (qq < 3) {   // prefetch next quarter during compute
#pragma unroll
        for (int h = 0; h < 2; ++h) {
          const int r = wave * 8 + h * 4 + srow4;
          const int id = doc[b * ND + (qq + 1) * 128 + r];
          __builtin_amdgcn_global_load_lds(
              AS1C(g_norm + (size_t)id * NE + ((slot ^ (r & 7)) * 8)),
              AS3C(nxt + (wave * 8 + h * 4) * NE), 16, 0, 0);
        }
      }
      // ---- MFMA: 16 d-rows x 16 q for this wave ----
      f32x4 acc = (f32x4){0.f, 0.f, 0.f, 0.f};
      const int R = dgg * 16 + lrow;
#pragma unroll
      for (int ks = 0; ks < 4; ++ks) {
        const int qs = (ks * 4 + lgrp) ^ (qrow & 7);
        short8 bq = *(const short8*)(qtile + qrow * NE + qs * 8);
        const int as = (ks * 4 + lgrp) ^ (R & 7);
        short8 a = *(const short8*)(cur + R * NE + as * 8);
        acc = __builtin_amdgcn_mfma_f32_16x16x32_bf16(a, bq, acc, 0, 0, 0);
      }
      // ---- recurrence pooling: 2 element-pairs, f32x2 ----
#pragma unroll
      for (int h = 0; h < 2; ++h) {
        f32x2 m2 = { acc[2 * h], acc[2 * h + 1] };
        f32x2 Aarg = m2 * ACOEF;
        f32x2 A2 = { __builtin_amdgcn_exp2f(Aarg.x), __builtin_amdgcn_exp2f(Aarg.y) };
#pragma unroll
        for (int j = 0; j < 5; ++j) {
          f32x2 arg = m2 * (m2 * Cc + Bc[j]) + Gc[j];
          f32x2 E2 = { __builtin_amdgcn_exp2f(arg.x), __builtin_amdgcn_exp2f(arg.y) };
          f32x2 W2 = A2 * Hc[j];
          s2[4 * j]     += E2;
          E2 *= W2; W2 *= Rr;
          s2[4 * j + 1] += E2;
          E2 *= W2; W2 *= Rr;
          s2[4 * j + 2] += E2;
          E2 *= W2;
          s2[4 * j + 3] += E2;
        }
      }
      __syncthreads();   // drains prefetch; orders buffer reuse
    }
  }

  // ---- fold pairs (scale by 1/REP) + wave reduce ----
  const float invrep = 1.0f / (float)REP;
  float s[20];
#pragma unroll
  for (int k = 0; k < 20; ++k) {
    s[k] = (s2[k].x + s2[k].y) * invrep;
    s[k] += __shfl_xor(s[k], 16);
    s[k] += __shfl_xor(s[k], 32);
  }
  float* Sw  = (float*)dtA;      // [16 waves][16 lrow][20 k] = 20480 B (dtA dead)
  float* buf = Sw + 5120;        // [NQ*NK]
  float* km  = buf + 640;        // [21]
  float* h1  = km + 32;          // [10]
  float* h2  = h1 + 16;          // [5]
  if (lgrp == 0) {
#pragma unroll
    for (int k = 0; k < 20; ++k) Sw[(wave * 16 + lrow) * 20 + k] = s[k];
  }
  __syncthreads();

  // ---- block reduce + log1p (one (q,k) per thread) ----
  if (t < NQ * NK) {
    const int q = t / NK, k = t % NK;
    float v;
    if (k < 20) {
      const int w0 = q >> 4;
      v = 0.f;
#pragma unroll
      for (int g = 0; g < 8; ++g) v += Sw[((g * 2 + w0) * 16 + (q & 15)) * 20 + k];
    } else {
      v = Sex[q];
    }
    buf[t] = log1pf(v);
  }
  __syncthreads();

  // ---- fused MLP 21->10->5->1 ----
  if (t < NK) {
    float acc0 = 0.f;
#pragma unroll 1
    for (int q = 0; q < NQ; ++q) acc0 += buf[q * NK + t];
    km[t] = acc0;
  }
  __syncthreads();
  if (t < 10) {
    float a = b1[t];
#pragma unroll 1
    for (int k = 0; k < NK; ++k) a = fmaf(km[k], w1[k * 10 + t], a);
    h1[t] = fmaxf(a, 0.f);
  }
  __syncthreads();
  if (t < 5) {
    float a = b2[t];
#pragma unroll 1
    for (int k = 0; k < 10; ++k) a = fmaf(h1[k], w2[k * 5 + t], a);
    h2[t] = fmaxf(a, 0.f);
  }
  __syncthreads();
  if (t == 0) {
    float a = b3[0];
#pragma unroll 1
    for (int k = 0; k < 5; ++k) a = fmaf(h2[k], w3[k], a);
    out[b] = a;
  }
}

extern "C" void kernel_launch(void* const* d_in, const int* in_sizes, int n_in,
                              void* d_out, int out_size, void* d_ws, size_t ws_size,
                              hipStream_t stream) {
  const int*   query = (const int*)d_in[0];
  const int*   doc   = (const int*)d_in[1];
  const float* emb   = (const float*)d_in[2];
  const float* w1    = (const float*)d_in[3];
  const float* b1    = (const float*)d_in[4];
  const float* w2    = (const float*)d_in[5];
  const float* b2    = (const float*)d_in[6];
  const float* w3    = (const float*)d_in[7];
  const float* b3    = (const float*)d_in[8];
  float* out = (float*)d_out;

  const size_t sh = (size_t)128 * NE * 2 * 2   // dtA + dtB  65536
                  + (size_t)32 * NE * 2        // qtile       8192
                  + 32 * 4;                    // Sex          128  -> 73856
  hipFuncSetAttribute((const void*)knrm_part,
                      hipFuncAttributeMaxDynamicSharedMemorySize, (int)sh);

  norm_kernel<<<dim3(VOCAB / 8), dim3(256), 0, stream>>>(emb);
  knrm_part<<<dim3(NB), dim3(1024), sh, stream>>>(
      query, doc, w1, b1, w2, b2, w3, b3, out);
}

// Round 15
// 74.711 us; speedup vs baseline: 1.6553x; 1.1165x over previous
//
#include <hip/hip_runtime.h>
#include <hip/hip_bf16.h>
#include <math.h>

#define NB 512
#define NQ 30
#define ND 512
#define NE 128
#define NK 21
#define VOCAB 50000
#define REP 3   // instrumentation: x3 compute passes, scaled by 1/3

typedef __attribute__((ext_vector_type(4))) float f32x4;
typedef __attribute__((ext_vector_type(2))) float f32x2;
typedef __attribute__((ext_vector_type(8))) short short8;

#define AS1C(p) ((const __attribute__((address_space(1))) unsigned int*)(p))
#define AS3C(p) ((__attribute__((address_space(3))) unsigned int*)(p))

// normalized vocab table, bf16 (12.8 MB). Fully rewritten every launch (idempotent).
__device__ unsigned short g_norm[(size_t)VOCAB * NE];
// per-(b,dhalf) partials for ALL 21 kernels (exact-match at k=20).
// Plain stores, every element rewritten every launch.
__device__ float g_Sp[(size_t)NB * 2 * NQ * NK];
// 256B of zeros for padding q-rows 30,31. Never written -> stays zero.
__device__ unsigned short g_zero[NE];

__device__ __forceinline__ unsigned short f2bf(float f) {
  unsigned int x = __builtin_bit_cast(unsigned int, f);
  x = (x + 0x7fffu + ((x >> 16) & 1u)) >> 16;   // RNE
  return (unsigned short)x;
}

// ---------------- kernel 1: normalize vocab to bf16 ----------------
__global__ __launch_bounds__(256) void norm_kernel(const float* __restrict__ emb) {
  const int t = threadIdx.x;
  const int row = blockIdx.x * 8 + (t >> 5);
  const int j = t & 31;
  const float* src = emb + (size_t)row * NE;
  float4 v = *(const float4*)(src + j * 4);
  float ssq = v.x * v.x + v.y * v.y + v.z * v.z + v.w * v.w;
  ssq += __shfl_xor(ssq, 1);
  ssq += __shfl_xor(ssq, 2);
  ssq += __shfl_xor(ssq, 4);
  ssq += __shfl_xor(ssq, 8);
  ssq += __shfl_xor(ssq, 16);
  const float sc = 1.0f / fmaxf(sqrtf(ssq), 1e-12f);
  ushort4 o;
  o.x = f2bf(v.x * sc); o.y = f2bf(v.y * sc);
  o.z = f2bf(v.z * sc); o.w = f2bf(v.w * sc);
  *(ushort4*)(g_norm + (size_t)row * NE + j * 4) = o;
}

// ---------------- kernel 2: partial KNRM (256 doc rows / block, 64-row chunks) ----
// 512 threads = 8 waves; wave w: qt=w&1 (16 q cols), dg=w>>1 (16 d rows/chunk).
// LDS: dtA 16K + dtB 16K + qtile 8K = 40960B exactly -> 4 blocks/CU (32 waves).
__global__ __launch_bounds__(512, 6) void knrm_part(
    const int* __restrict__ query, const int* __restrict__ doc)
{
  extern __shared__ unsigned char smem_raw[];
  unsigned short* dtA   = (unsigned short*)smem_raw;    // [64][128] bf16, slot-swizzled
  unsigned short* dtB   = dtA + 64 * NE;                // [64][128]
  unsigned short* qtile = dtB + 64 * NE;                // [32][128]

  const int t = threadIdx.x;
  const unsigned bid = blockIdx.x;
  const int b  = bid >> 1;
  const int d0 = (bid & 1) * 256;

  const int wave = t >> 6, lane = t & 63;
  const int srow4 = lane >> 4, slot = lane & 15;
  const int lrow = lane & 15, lgrp = lane >> 4;
  const int qt = wave & 1, dg = wave >> 1;   // dg in 0..3

  // ---- stage qtile (once): 8 waves x 4 rows ----
  {
    const int qr = wave * 4 + srow4;
    const unsigned short* srcrow =
        (qr < NQ) ? (g_norm + (size_t)query[b * NQ + qr] * NE) : g_zero;
    __builtin_amdgcn_global_load_lds(AS1C(srcrow + ((slot ^ (qr & 7)) * 8)),
                                     AS3C(qtile + (wave * 4) * NE), 16, 0, 0);
  }
  // ---- stage chunk 0 into dtA: each wave 8 rows = 2 ops ----
#pragma unroll
  for (int h = 0; h < 2; ++h) {
    const int r = wave * 8 + h * 4 + srow4;             // local row 0..63
    const int id = doc[b * ND + d0 + r];
    __builtin_amdgcn_global_load_lds(
        AS1C(g_norm + (size_t)id * NE + ((slot ^ (r & 7)) * 8)),
        AS3C(dtA + (wave * 8 + h * 4) * NE), 16, 0, 0);
  }
  __syncthreads();

  // recurrence constants (Cc*ln2 = -50 exactly)
  const float Cc = -72.13475204444817f;           // -50/ln2
  const float ACOEF = 14.426950408889634f;        // 10/ln2 : A = e^{10m}
  const float Rr = 0.36787944117144233f;          // e^-1
  const float Hc[5] = { 8103.083927575384f, 148.4131591025766f,
                        2.718281828459045f, 0.049787068367863944f,
                        0.0009118819655545162f }; // e^{-10*mu_k0 - 0.5}
  const float Bc[5] = { -137.05602888445152f, -79.34822724889299f,
                        -21.64042561333445f, 36.067376022224085f,
                        93.77517765778262f };     // -2*Cc*mu_k0
  const float Gc[5] = { -65.10161372011448f, -21.820762493445572f,
                        -1.6230319210000838f, -4.508422002778011f,
                        -30.47693273877935f };    // Cc*mu_k0^2

  f32x2 s2[20];
#pragma unroll
  for (int k = 0; k < 20; ++k) s2[k] = (f32x2){0.f, 0.f};

  const int qrow = qt * 16 + lrow;
  const int R = dg * 16 + lrow;                   // local d-row for MFMA A

#pragma unroll 1
  for (int rep = 0; rep < REP; ++rep) {
#pragma unroll 1
    for (int qq = 0; qq < 4; ++qq) {
      unsigned short* cur = (qq & 1) ? dtB : dtA;
      unsigned short* nxt = (qq & 1) ? dtA : dtB;
      // prefetch next chunk (wraps to chunk 0 across rep boundary)
      if (qq < 3 || rep < REP - 1) {
        const int nc = (qq + 1) & 3;
#pragma unroll
        for (int h = 0; h < 2; ++h) {
          const int r = wave * 8 + h * 4 + srow4;
          const int id = doc[b * ND + d0 + nc * 64 + r];
          __builtin_amdgcn_global_load_lds(
              AS1C(g_norm + (size_t)id * NE + ((slot ^ (r & 7)) * 8)),
              AS3C(nxt + (wave * 8 + h * 4) * NE), 16, 0, 0);
        }
      }
      // ---- MFMA: 16 d-rows x 16 q for this wave ----
      f32x4 acc = (f32x4){0.f, 0.f, 0.f, 0.f};
#pragma unroll
      for (int ks = 0; ks < 4; ++ks) {
        const int qs = (ks * 4 + lgrp) ^ (qrow & 7);
        short8 bq = *(const short8*)(qtile + qrow * NE + qs * 8);
        const int as = (ks * 4 + lgrp) ^ (R & 7);
        short8 a = *(const short8*)(cur + R * NE + as * 8);
        acc = __builtin_amdgcn_mfma_f32_16x16x32_bf16(a, bq, acc, 0, 0, 0);
      }
      // ---- recurrence pooling: 2 element-pairs, f32x2 ----
#pragma unroll
      for (int h = 0; h < 2; ++h) {
        f32x2 m2 = { acc[2 * h], acc[2 * h + 1] };
        f32x2 Aarg = m2 * ACOEF;
        f32x2 A2 = { __builtin_amdgcn_exp2f(Aarg.x), __builtin_amdgcn_exp2f(Aarg.y) };
#pragma unroll
        for (int j = 0; j < 5; ++j) {
          f32x2 arg = m2 * (m2 * Cc + Bc[j]) + Gc[j];
          f32x2 E2 = { __builtin_amdgcn_exp2f(arg.x), __builtin_amdgcn_exp2f(arg.y) };
          f32x2 W2 = A2 * Hc[j];
          s2[4 * j]     += E2;
          E2 *= W2; W2 *= Rr;
          s2[4 * j + 1] += E2;
          E2 *= W2; W2 *= Rr;
          s2[4 * j + 2] += E2;
          E2 *= W2;
          s2[4 * j + 3] += E2;
        }
      }
      __syncthreads();   // drains prefetch; orders buffer reuse
    }
  }

  // ---- fold pairs (scale by 1/REP) + wave reduce ----
  const float invrep = 1.0f / (float)REP;
  float s[20];
#pragma unroll
  for (int k = 0; k < 20; ++k) {
    s[k] = (s2[k].x + s2[k].y) * invrep;
    s[k] += __shfl_xor(s[k], 16);
    s[k] += __shfl_xor(s[k], 32);
  }
  // LDS tiles dead -> scratch: Sw [8][16][20] + Sex[32]
  float* Sw  = (float*)dtA;
  float* Sex = Sw + 8 * 16 * 20;
  if (lgrp == 0) {
#pragma unroll
    for (int k = 0; k < 20; ++k) Sw[(wave * 16 + lrow) * 20 + k] = s[k];
  }
  if (t < 32) Sex[t] = 0.0f;
  __syncthreads();

  // ---- exact-match kernel (mu=1, sigma=0.001): integer ID equality ----
  if (t < 256) {
    const int did = doc[b * ND + d0 + t];
    const int* qp = query + b * NQ;   // uniform -> scalar loads
#pragma unroll 1
    for (int q = 0; q < NQ; ++q)
      if (did == qp[q]) atomicAdd(&Sex[q], 1.0f);   // block-local, +1.0 only
  }
  __syncthreads();

  // ---- block reduce -> plain store of 21 kernels for this (b,dhalf) ----
  for (int i = t; i < NQ * NK; i += 512) {
    const int q = i / NK, k = i % NK;
    float v;
    if (k < 20) {
      const int w0 = q >> 4;
      v = 0.f;
#pragma unroll
      for (int g = 0; g < 4; ++g) v += Sw[((g * 2 + w0) * 16 + (q & 15)) * 20 + k];
    } else {
      v = Sex[q];
    }
    g_Sp[(size_t)bid * NQ * NK + i] = v;
  }
}

// ---------------- kernel 3: log1p + MLP ----------------
__global__ __launch_bounds__(640) void knrm_finish(
    const float* __restrict__ w1, const float* __restrict__ b1,
    const float* __restrict__ w2, const float* __restrict__ b2,
    const float* __restrict__ w3, const float* __restrict__ b3,
    float* __restrict__ out)
{
  __shared__ float buf[NQ * NK];
  __shared__ float km[NK], h1[10], h2[5];
  const int b = blockIdx.x, t = threadIdx.x;
  if (t < NQ * NK) {
    const float* base = g_Sp + (size_t)(b * 2) * NQ * NK + t;
    buf[t] = log1pf(base[0] + base[NQ * NK]);
  }
  __syncthreads();
  if (t < NK) {
    float s = 0.f;
#pragma unroll 1
    for (int q = 0; q < NQ; ++q) s += buf[q * NK + t];
    km[t] = s;
  }
  __syncthreads();
  if (t < 10) {
    float a = b1[t];
#pragma unroll 1
    for (int k = 0; k < NK; ++k) a = fmaf(km[k], w1[k * 10 + t], a);
    h1[t] = fmaxf(a, 0.f);
  }
  __syncthreads();
  if (t < 5) {
    float a = b2[t];
#pragma unroll 1
    for (int k = 0; k < 10; ++k) a = fmaf(h1[k], w2[k * 5 + t], a);
    h2[t] = fmaxf(a, 0.f);
  }
  __syncthreads();
  if (t == 0) {
    float a = b3[0];
#pragma unroll 1
    for (int k = 0; k < 5; ++k) a = fmaf(h2[k], w3[k], a);
    out[b] = a;
  }
}

extern "C" void kernel_launch(void* const* d_in, const int* in_sizes, int n_in,
                              void* d_out, int out_size, void* d_ws, size_t ws_size,
                              hipStream_t stream) {
  const int*   query = (const int*)d_in[0];
  const int*   doc   = (const int*)d_in[1];
  const float* emb   = (const float*)d_in[2];
  const float* w1    = (const float*)d_in[3];
  const float* b1    = (const float*)d_in[4];
  const float* w2    = (const float*)d_in[5];
  const float* b2    = (const float*)d_in[6];
  const float* w3    = (const float*)d_in[7];
  const float* b3    = (const float*)d_in[8];
  float* out = (float*)d_out;

  const size_t sh = (size_t)64 * NE * 2 * 2    // dtA + dtB  32768
                  + (size_t)32 * NE * 2;       // qtile       8192  -> 40960 exactly
  hipFuncSetAttribute((const void*)knrm_part,
                      hipFuncAttributeMaxDynamicSharedMemorySize, (int)sh);

  norm_kernel<<<dim3(VOCAB / 8), dim3(256), 0, stream>>>(emb);
  knrm_part<<<dim3(NB * 2), dim3(512), sh, stream>>>(query, doc);
  knrm_finish<<<dim3(NB), dim3(640), 0, stream>>>(w1, b1, w2, b2, w3, b3, out);
}

// Round 16
// 48.255 us; speedup vs baseline: 2.5628x; 1.5483x over previous
//
#include <hip/hip_runtime.h>
#include <hip/hip_bf16.h>
#include <math.h>

#define NB 512
#define NQ 30
#define ND 512
#define NE 128
#define NK 21
#define VOCAB 50000

typedef __attribute__((ext_vector_type(4))) float f32x4;
typedef __attribute__((ext_vector_type(2))) float f32x2;
typedef __attribute__((ext_vector_type(8))) short short8;

#define AS1C(p) ((const __attribute__((address_space(1))) unsigned int*)(p))
#define AS3C(p) ((__attribute__((address_space(3))) unsigned int*)(p))

// packed fp32 (VOP3P, 64-bit VGPR-pair operands), in-place
#define PK_ADD(d, s) asm("v_pk_add_f32 %0, %0, %1" : "+v"(d) : "v"(s))
#define PK_MUL(d, s) asm("v_pk_mul_f32 %0, %0, %1" : "+v"(d) : "v"(s))

// normalized vocab table, bf16 (12.8 MB). Fully rewritten every launch (idempotent).
__device__ unsigned short g_norm[(size_t)VOCAB * NE];
// per-(b,dhalf) partials for ALL 21 kernels (exact-match at k=20).
__device__ float g_Sp[(size_t)NB * 2 * NQ * NK];
// 256B of zeros for padding q-rows 30,31. Never written -> stays zero.
__device__ unsigned short g_zero[NE];

__device__ __forceinline__ unsigned short f2bf(float f) {
  unsigned int x = __builtin_bit_cast(unsigned int, f);
  x = (x + 0x7fffu + ((x >> 16) & 1u)) >> 16;   // RNE
  return (unsigned short)x;
}

__device__ __forceinline__ f32x2 exp2x2(f32x2 a) {
  return (f32x2){__builtin_amdgcn_exp2f(a.x), __builtin_amdgcn_exp2f(a.y)};
}

// ---------------- kernel 1: normalize vocab to bf16 ----------------
__global__ __launch_bounds__(256) void norm_kernel(const float* __restrict__ emb) {
  const int t = threadIdx.x;
  const int row = blockIdx.x * 8 + (t >> 5);
  const int j = t & 31;
  const float* src = emb + (size_t)row * NE;
  float4 v = *(const float4*)(src + j * 4);
  float ssq = v.x * v.x + v.y * v.y + v.z * v.z + v.w * v.w;
  ssq += __shfl_xor(ssq, 1);
  ssq += __shfl_xor(ssq, 2);
  ssq += __shfl_xor(ssq, 4);
  ssq += __shfl_xor(ssq, 8);
  ssq += __shfl_xor(ssq, 16);
  const float sc = 1.0f / fmaxf(sqrtf(ssq), 1e-12f);
  ushort4 o;
  o.x = f2bf(v.x * sc); o.y = f2bf(v.y * sc);
  o.z = f2bf(v.z * sc); o.w = f2bf(v.w * sc);
  *(ushort4*)(g_norm + (size_t)row * NE + j * 4) = o;
}

// ---------------- kernel 2: partial KNRM (256 doc rows / block, 64-row chunks) ----
// 512 threads = 8 waves; wave w: qt=w&1 (16 q cols), dg=w>>1 (16 d rows/chunk).
// LDS: dtA 16K + dtB 16K + qtile 8K = 40960B exactly -> 4 blocks/CU.
__global__ __launch_bounds__(512, 5) void knrm_part(
    const int* __restrict__ query, const int* __restrict__ doc)
{
  extern __shared__ unsigned char smem_raw[];
  unsigned short* dtA   = (unsigned short*)smem_raw;    // [64][128] bf16, slot-swizzled
  unsigned short* dtB   = dtA + 64 * NE;                // [64][128]
  unsigned short* qtile = dtB + 64 * NE;                // [32][128]

  const int t = threadIdx.x;
  const unsigned bid = blockIdx.x;
  const int b  = bid >> 1;
  const int d0 = (bid & 1) * 256;

  const int wave = t >> 6, lane = t & 63;
  const int srow4 = lane >> 4, slot = lane & 15;
  const int lrow = lane & 15, lgrp = lane >> 4;
  const int qt = wave & 1, dg = wave >> 1;   // dg in 0..3

  // ---- stage qtile (once): 8 waves x 4 rows ----
  {
    const int qr = wave * 4 + srow4;
    const unsigned short* srcrow =
        (qr < NQ) ? (g_norm + (size_t)query[b * NQ + qr] * NE) : g_zero;
    __builtin_amdgcn_global_load_lds(AS1C(srcrow + ((slot ^ (qr & 7)) * 8)),
                                     AS3C(qtile + (wave * 4) * NE), 16, 0, 0);
  }
  // ---- stage chunk 0 into dtA ----
#pragma unroll
  for (int h = 0; h < 2; ++h) {
    const int r = wave * 8 + h * 4 + srow4;             // local row 0..63
    const int id = doc[b * ND + d0 + r];
    __builtin_amdgcn_global_load_lds(
        AS1C(g_norm + (size_t)id * NE + ((slot ^ (r & 7)) * 8)),
        AS3C(dtA + (wave * 8 + h * 4) * NE), 16, 0, 0);
  }
  __syncthreads();

  // constants (Cc*ln2 = -50 exactly: e-clean recurrence)
  const float Cc    = -72.13475204444817f;   // -50/ln2
  const float ACOEF = 14.426950408889634f;   // 10/ln2
  const float AOFF  = 12.984255368000671f;   // 9/ln2  (folds Hc0 = e^9 into A)
  const f32x2 Rr2   = {0.36787944117144233f, 0.36787944117144233f};   // e^-1
  const f32x2 E2I2  = {0.1353352832366127f,  0.1353352832366127f};    // e^-2
  const float Bc[5] = { -137.05602888445152f, -79.34822724889299f,
                        -21.64042561333445f, 36.067376022224085f,
                        93.77517765778262f };     // -2*Cc*mu_{4j}
  const float Gc[5] = { -65.10161372011448f, -21.820762493445572f,
                        -1.6230319210000838f, -4.508422002778011f,
                        -30.47693273877935f };    // Cc*mu_{4j}^2

  f32x2 s2[20];
#pragma unroll
  for (int k = 0; k < 20; ++k) s2[k] = (f32x2){0.f, 0.f};

  const int qrow = qt * 16 + lrow;
  const int R = dg * 16 + lrow;

#pragma unroll 1
  for (int qq = 0; qq < 4; ++qq) {
    unsigned short* cur = (qq & 1) ? dtB : dtA;
    unsigned short* nxt = (qq & 1) ? dtA : dtB;
    if (qq < 3) {   // prefetch next chunk during compute
#pragma unroll
      for (int h = 0; h < 2; ++h) {
        const int r = wave * 8 + h * 4 + srow4;
        const int id = doc[b * ND + d0 + (qq + 1) * 64 + r];
        __builtin_amdgcn_global_load_lds(
            AS1C(g_norm + (size_t)id * NE + ((slot ^ (r & 7)) * 8)),
            AS3C(nxt + (wave * 8 + h * 4) * NE), 16, 0, 0);
      }
    }
    // ---- MFMA: 16 d-rows x 16 q for this wave ----
    f32x4 acc = (f32x4){0.f, 0.f, 0.f, 0.f};
#pragma unroll
    for (int ks = 0; ks < 4; ++ks) {
      const int qs = (ks * 4 + lgrp) ^ (qrow & 7);
      short8 bq = *(const short8*)(qtile + qrow * NE + qs * 8);
      const int as = (ks * 4 + lgrp) ^ (R & 7);
      short8 a = *(const short8*)(cur + R * NE + as * 8);
      acc = __builtin_amdgcn_mfma_f32_16x16x32_bf16(a, bq, acc, 0, 0, 0);
    }
    // ---- recurrence pooling, packed f32 chain ----
#pragma unroll
    for (int h = 0; h < 2; ++h) {
      f32x2 m2 = { acc[2 * h], acc[2 * h + 1] };
      // W = A*Hc0 = exp2(m*10/ln2 + 9/ln2)
      f32x2 W = exp2x2((f32x2){ fmaf(m2.x, ACOEF, AOFF),
                                fmaf(m2.y, ACOEF, AOFF) });
#pragma unroll
      for (int j = 0; j < 5; ++j) {
        f32x2 E = exp2x2((f32x2){ fmaf(m2.x, fmaf(Cc, m2.x, Bc[j]), Gc[j]),
                                  fmaf(m2.y, fmaf(Cc, m2.y, Bc[j]), Gc[j]) });
        PK_ADD(s2[4 * j], E);          // k = 4j
        PK_MUL(E, W);
        PK_ADD(s2[4 * j + 1], E);      // k = 4j+1
        PK_MUL(W, Rr2);
        PK_MUL(E, W);
        PK_ADD(s2[4 * j + 2], E);      // k = 4j+2
        PK_MUL(W, Rr2);
        PK_MUL(E, W);
        PK_ADD(s2[4 * j + 3], E);      // k = 4j+3
        if (j < 4) PK_MUL(W, E2I2);    // W -> A*Hc_{j+1} (=W*e^-4 total)
      }
    }
    __syncthreads();   // drains prefetch; orders buffer reuse
  }

  // ---- fold pairs + wave reduce: lanes<16 hold full wave sums ----
  float s[20];
#pragma unroll
  for (int k = 0; k < 20; ++k) {
    s[k] = s2[k].x + s2[k].y;
    s[k] += __shfl_xor(s[k], 16);
    s[k] += __shfl_xor(s[k], 32);
  }
  // LDS tiles dead -> scratch: Sw [8][16][20] + Sex[32]
  float* Sw  = (float*)dtA;
  float* Sex = Sw + 8 * 16 * 20;
  if (lgrp == 0) {
#pragma unroll
    for (int k = 0; k < 20; ++k) Sw[(wave * 16 + lrow) * 20 + k] = s[k];
  }
  if (t < 32) Sex[t] = 0.0f;
  __syncthreads();

  // ---- exact-match kernel (mu=1, sigma=0.001): integer ID equality ----
  if (t < 256) {
    const int did = doc[b * ND + d0 + t];
    const int* qp = query + b * NQ;   // uniform -> scalar loads
#pragma unroll 1
    for (int q = 0; q < NQ; ++q)
      if (did == qp[q]) atomicAdd(&Sex[q], 1.0f);   // block-local, +1.0 only
  }
  __syncthreads();

  // ---- block reduce -> plain store of 21 kernels for this (b,dhalf) ----
  for (int i = t; i < NQ * NK; i += 512) {
    const int q = i / NK, k = i % NK;
    float v;
    if (k < 20) {
      const int w0 = q >> 4;
      v = 0.f;
#pragma unroll
      for (int g = 0; g < 4; ++g) v += Sw[((g * 2 + w0) * 16 + (q & 15)) * 20 + k];
    } else {
      v = Sex[q];
    }
    g_Sp[(size_t)bid * NQ * NK + i] = v;
  }
}

// ---------------- kernel 3: log1p + MLP ----------------
__global__ __launch_bounds__(640) void knrm_finish(
    const float* __restrict__ w1, const float* __restrict__ b1,
    const float* __restrict__ w2, const float* __restrict__ b2,
    const float* __restrict__ w3, const float* __restrict__ b3,
    float* __restrict__ out)
{
  __shared__ float buf[NQ * NK];
  __shared__ float km[NK], h1[10], h2[5];
  const int b = blockIdx.x, t = threadIdx.x;
  if (t < NQ * NK) {
    const float* base = g_Sp + (size_t)(b * 2) * NQ * NK + t;
    buf[t] = log1pf(base[0] + base[NQ * NK]);
  }
  __syncthreads();
  if (t < NK) {
    float s = 0.f;
#pragma unroll 1
    for (int q = 0; q < NQ; ++q) s += buf[q * NK + t];
    km[t] = s;
  }
  __syncthreads();
  if (t < 10) {
    float a = b1[t];
#pragma unroll 1
    for (int k = 0; k < NK; ++k) a = fmaf(km[k], w1[k * 10 + t], a);
    h1[t] = fmaxf(a, 0.f);
  }
  __syncthreads();
  if (t < 5) {
    float a = b2[t];
#pragma unroll 1
    for (int k = 0; k < 10; ++k) a = fmaf(h1[k], w2[k * 5 + t], a);
    h2[t] = fmaxf(a, 0.f);
  }
  __syncthreads();
  if (t == 0) {
    float a = b3[0];
#pragma unroll 1
    for (int k = 0; k < 5; ++k) a = fmaf(h2[k], w3[k], a);
    out[b] = a;
  }
}

extern "C" void kernel_launch(void* const* d_in, const int* in_sizes, int n_in,
                              void* d_out, int out_size, void* d_ws, size_t ws_size,
                              hipStream_t stream) {
  const int*   query = (const int*)d_in[0];
  const int*   doc   = (const int*)d_in[1];
  const float* emb   = (const float*)d_in[2];
  const float* w1    = (const float*)d_in[3];
  const float* b1    = (const float*)d_in[4];
  const float* w2    = (const float*)d_in[5];
  const float* b2    = (const float*)d_in[6];
  const float* w3    = (const float*)d_in[7];
  const float* b3    = (const float*)d_in[8];
  float* out = (float*)d_out;

  const size_t sh = (size_t)64 * NE * 2 * 2    // dtA + dtB  32768
                  + (size_t)32 * NE * 2;       // qtile       8192  -> 40960 exactly
  hipFuncSetAttribute((const void*)knrm_part,
                      hipFuncAttributeMaxDynamicSharedMemorySize, (int)sh);

  norm_kernel<<<dim3(VOCAB / 8), dim3(256), 0, stream>>>(emb);
  knrm_part<<<dim3(NB * 2), dim3(512), sh, stream>>>(query, doc);
  knrm_finish<<<dim3(NB), dim3(640), 0, stream>>>(w1, b1, w2, b2, w3, b3, out);
}

// Round 17
// 48.168 us; speedup vs baseline: 2.5674x; 1.0018x over previous
//
#include <hip/hip_runtime.h>
#include <hip/hip_bf16.h>
#include <math.h>

#define NB 512
#define NQ 30
#define ND 512
#define NE 128
#define NK 21
#define VOCAB 50000

typedef __attribute__((ext_vector_type(4))) float f32x4;
typedef __attribute__((ext_vector_type(2))) float f32x2;
typedef __attribute__((ext_vector_type(8))) short short8;

#define AS1C(p) ((const __attribute__((address_space(1))) unsigned int*)(p))
#define AS3C(p) ((__attribute__((address_space(3))) unsigned int*)(p))

// packed fp32 (VOP3P, 64-bit VGPR-pair operands), in-place
#define PK_ADD(d, s) asm("v_pk_add_f32 %0, %0, %1" : "+v"(d) : "v"(s))
#define PK_MUL(d, s) asm("v_pk_mul_f32 %0, %0, %1" : "+v"(d) : "v"(s))

// normalized vocab table, bf16 (12.8 MB). Fully rewritten every launch (idempotent).
__device__ unsigned short g_norm[(size_t)VOCAB * NE];
// per-(b,dhalf) partials for ALL 21 kernels (exact-match at k=20).
__device__ float g_Sp[(size_t)NB * 2 * NQ * NK];
// 256B of zeros for padding q-rows 30,31. Never written -> stays zero.
__device__ unsigned short g_zero[NE];

__device__ __forceinline__ unsigned short f2bf(float f) {
  unsigned int x = __builtin_bit_cast(unsigned int, f);
  x = (x + 0x7fffu + ((x >> 16) & 1u)) >> 16;   // RNE
  return (unsigned short)x;
}

__device__ __forceinline__ f32x2 exp2x2(f32x2 a) {
  return (f32x2){__builtin_amdgcn_exp2f(a.x), __builtin_amdgcn_exp2f(a.y)};
}

// ---------------- kernel 1: normalize vocab to bf16 ----------------
__global__ __launch_bounds__(256) void norm_kernel(const float* __restrict__ emb) {
  const int t = threadIdx.x;
  const int row = blockIdx.x * 8 + (t >> 5);
  const int j = t & 31;
  const float* src = emb + (size_t)row * NE;
  float4 v = *(const float4*)(src + j * 4);
  float ssq = v.x * v.x + v.y * v.y + v.z * v.z + v.w * v.w;
  ssq += __shfl_xor(ssq, 1);
  ssq += __shfl_xor(ssq, 2);
  ssq += __shfl_xor(ssq, 4);
  ssq += __shfl_xor(ssq, 8);
  ssq += __shfl_xor(ssq, 16);
  const float sc = 1.0f / fmaxf(sqrtf(ssq), 1e-12f);
  ushort4 o;
  o.x = f2bf(v.x * sc); o.y = f2bf(v.y * sc);
  o.z = f2bf(v.z * sc); o.w = f2bf(v.w * sc);
  *(ushort4*)(g_norm + (size_t)row * NE + j * 4) = o;
}

// ---------------- kernel 2: partial KNRM (256 doc rows / block, 64-row chunks) ----
// 512 threads = 8 waves; wave w: qt=w&1 (16 q cols), dg=w>>1 (16 d rows/chunk).
// LDS: dtA 16K + dtB 16K + qtile 8K = 40960B exactly.
// launch_bounds(512,4): unified VGPR budget 128/thread so s2[20] (40 regs) stays
// in ARCH VGPRs. At (512,5/6) the allocator met the waves-target by parking s2 in
// AGPRs (counters: VGPR_Count=40-56 < live set) -> every accumulate paid
// accvgpr_read/write round-trips (the inline-asm "v" constraints force arch VGPRs)
// => ~6x VALU bloat, VALUBusy pinned ~50%, part stuck ~30us across R12-R16.
__global__ __launch_bounds__(512, 4) void knrm_part(
    const int* __restrict__ query, const int* __restrict__ doc)
{
  extern __shared__ unsigned char smem_raw[];
  unsigned short* dtA   = (unsigned short*)smem_raw;    // [64][128] bf16, slot-swizzled
  unsigned short* dtB   = dtA + 64 * NE;                // [64][128]
  unsigned short* qtile = dtB + 64 * NE;                // [32][128]

  const int t = threadIdx.x;
  const unsigned bid = blockIdx.x;
  const int b  = bid >> 1;
  const int d0 = (bid & 1) * 256;

  const int wave = t >> 6, lane = t & 63;
  const int srow4 = lane >> 4, slot = lane & 15;
  const int lrow = lane & 15, lgrp = lane >> 4;
  const int qt = wave & 1, dg = wave >> 1;   // dg in 0..3

  // ---- stage qtile (once): 8 waves x 4 rows ----
  {
    const int qr = wave * 4 + srow4;
    const unsigned short* srcrow =
        (qr < NQ) ? (g_norm + (size_t)query[b * NQ + qr] * NE) : g_zero;
    __builtin_amdgcn_global_load_lds(AS1C(srcrow + ((slot ^ (qr & 7)) * 8)),
                                     AS3C(qtile + (wave * 4) * NE), 16, 0, 0);
  }
  // ---- stage chunk 0 into dtA ----
#pragma unroll
  for (int h = 0; h < 2; ++h) {
    const int r = wave * 8 + h * 4 + srow4;             // local row 0..63
    const int id = doc[b * ND + d0 + r];
    __builtin_amdgcn_global_load_lds(
        AS1C(g_norm + (size_t)id * NE + ((slot ^ (r & 7)) * 8)),
        AS3C(dtA + (wave * 8 + h * 4) * NE), 16, 0, 0);
  }
  __syncthreads();

  // constants (Cc*ln2 = -50 exactly: e-clean recurrence)
  const float Cc    = -72.13475204444817f;   // -50/ln2
  const float ACOEF = 14.426950408889634f;   // 10/ln2
  const float AOFF  = 12.984255368000671f;   // 9/ln2  (folds Hc0 = e^9 into A)
  const f32x2 Rr2   = {0.36787944117144233f, 0.36787944117144233f};   // e^-1
  const f32x2 E2I2  = {0.1353352832366127f,  0.1353352832366127f};    // e^-2
  const float Bc[5] = { -137.05602888445152f, -79.34822724889299f,
                        -21.64042561333445f, 36.067376022224085f,
                        93.77517765778262f };     // -2*Cc*mu_{4j}
  const float Gc[5] = { -65.10161372011448f, -21.820762493445572f,
                        -1.6230319210000838f, -4.508422002778011f,
                        -30.47693273877935f };    // Cc*mu_{4j}^2

  f32x2 s2[20];
#pragma unroll
  for (int k = 0; k < 20; ++k) s2[k] = (f32x2){0.f, 0.f};

  const int qrow = qt * 16 + lrow;
  const int R = dg * 16 + lrow;

#pragma unroll 1
  for (int qq = 0; qq < 4; ++qq) {
    unsigned short* cur = (qq & 1) ? dtB : dtA;
    unsigned short* nxt = (qq & 1) ? dtA : dtB;
    if (qq < 3) {   // prefetch next chunk during compute
#pragma unroll
      for (int h = 0; h < 2; ++h) {
        const int r = wave * 8 + h * 4 + srow4;
        const int id = doc[b * ND + d0 + (qq + 1) * 64 + r];
        __builtin_amdgcn_global_load_lds(
            AS1C(g_norm + (size_t)id * NE + ((slot ^ (r & 7)) * 8)),
            AS3C(nxt + (wave * 8 + h * 4) * NE), 16, 0, 0);
      }
    }
    // ---- MFMA: 16 d-rows x 16 q for this wave ----
    f32x4 acc = (f32x4){0.f, 0.f, 0.f, 0.f};
#pragma unroll
    for (int ks = 0; ks < 4; ++ks) {
      const int qs = (ks * 4 + lgrp) ^ (qrow & 7);
      short8 bq = *(const short8*)(qtile + qrow * NE + qs * 8);
      const int as = (ks * 4 + lgrp) ^ (R & 7);
      short8 a = *(const short8*)(cur + R * NE + as * 8);
      acc = __builtin_amdgcn_mfma_f32_16x16x32_bf16(a, bq, acc, 0, 0, 0);
    }
    // ---- recurrence pooling, packed f32 chain ----
#pragma unroll
    for (int h = 0; h < 2; ++h) {
      f32x2 m2 = { acc[2 * h], acc[2 * h + 1] };
      // W = A*Hc0 = exp2(m*10/ln2 + 9/ln2)
      f32x2 W = exp2x2((f32x2){ fmaf(m2.x, ACOEF, AOFF),
                                fmaf(m2.y, ACOEF, AOFF) });
#pragma unroll
      for (int j = 0; j < 5; ++j) {
        f32x2 E = exp2x2((f32x2){ fmaf(m2.x, fmaf(Cc, m2.x, Bc[j]), Gc[j]),
                                  fmaf(m2.y, fmaf(Cc, m2.y, Bc[j]), Gc[j]) });
        PK_ADD(s2[4 * j], E);          // k = 4j
        PK_MUL(E, W);
        PK_ADD(s2[4 * j + 1], E);      // k = 4j+1
        PK_MUL(W, Rr2);
        PK_MUL(E, W);
        PK_ADD(s2[4 * j + 2], E);      // k = 4j+2
        PK_MUL(W, Rr2);
        PK_MUL(E, W);
        PK_ADD(s2[4 * j + 3], E);      // k = 4j+3
        if (j < 4) PK_MUL(W, E2I2);    // W -> A*Hc_{j+1} (=W*e^-4 total)
      }
    }
    __syncthreads();   // drains prefetch; orders buffer reuse
  }

  // ---- fold pairs + wave reduce: lanes<16 hold full wave sums ----
  float s[20];
#pragma unroll
  for (int k = 0; k < 20; ++k) {
    s[k] = s2[k].x + s2[k].y;
    s[k] += __shfl_xor(s[k], 16);
    s[k] += __shfl_xor(s[k], 32);
  }
  // LDS tiles dead -> scratch: Sw [8][16][20] + Sex[32]
  float* Sw  = (float*)dtA;
  float* Sex = Sw + 8 * 16 * 20;
  if (lgrp == 0) {
#pragma unroll
    for (int k = 0; k < 20; ++k) Sw[(wave * 16 + lrow) * 20 + k] = s[k];
  }
  if (t < 32) Sex[t] = 0.0f;
  __syncthreads();

  // ---- exact-match kernel (mu=1, sigma=0.001): integer ID equality ----
  if (t < 256) {
    const int did = doc[b * ND + d0 + t];
    const int* qp = query + b * NQ;   // uniform -> scalar loads
#pragma unroll 1
    for (int q = 0; q < NQ; ++q)
      if (did == qp[q]) atomicAdd(&Sex[q], 1.0f);   // block-local, +1.0 only
  }
  __syncthreads();

  // ---- block reduce -> plain store of 21 kernels for this (b,dhalf) ----
  for (int i = t; i < NQ * NK; i += 512) {
    const int q = i / NK, k = i % NK;
    float v;
    if (k < 20) {
      const int w0 = q >> 4;
      v = 0.f;
#pragma unroll
      for (int g = 0; g < 4; ++g) v += Sw[((g * 2 + w0) * 16 + (q & 15)) * 20 + k];
    } else {
      v = Sex[q];
    }
    g_Sp[(size_t)bid * NQ * NK + i] = v;
  }
}

// ---------------- kernel 3: log1p + MLP ----------------
__global__ __launch_bounds__(640) void knrm_finish(
    const float* __restrict__ w1, const float* __restrict__ b1,
    const float* __restrict__ w2, const float* __restrict__ b2,
    const float* __restrict__ w3, const float* __restrict__ b3,
    float* __restrict__ out)
{
  __shared__ float buf[NQ * NK];
  __shared__ float km[NK], h1[10], h2[5];
  const int b = blockIdx.x, t = threadIdx.x;
  if (t < NQ * NK) {
    const float* base = g_Sp + (size_t)(b * 2) * NQ * NK + t;
    buf[t] = log1pf(base[0] + base[NQ * NK]);
  }
  __syncthreads();
  if (t < NK) {
    float s = 0.f;
#pragma unroll 1
    for (int q = 0; q < NQ; ++q) s += buf[q * NK + t];
    km[t] = s;
  }
  __syncthreads();
  if (t < 10) {
    float a = b1[t];
#pragma unroll 1
    for (int k = 0; k < NK; ++k) a = fmaf(km[k], w1[k * 10 + t], a);
    h1[t] = fmaxf(a, 0.f);
  }
  __syncthreads();
  if (t < 5) {
    float a = b2[t];
#pragma unroll 1
    for (int k = 0; k < 10; ++k) a = fmaf(h1[k], w2[k * 5 + t], a);
    h2[t] = fmaxf(a, 0.f);
  }
  __syncthreads();
  if (t == 0) {
    float a = b3[0];
#pragma unroll 1
    for (int k = 0; k < 5; ++k) a = fmaf(h2[k], w3[k], a);
    out[b] = a;
  }
}

extern "C" void kernel_launch(void* const* d_in, const int* in_sizes, int n_in,
                              void* d_out, int out_size, void* d_ws, size_t ws_size,
                              hipStream_t stream) {
  const int*   query = (const int*)d_in[0];
  const int*   doc   = (const int*)d_in[1];
  const float* emb   = (const float*)d_in[2];
  const float* w1    = (const float*)d_in[3];
  const float* b1    = (const float*)d_in[4];
  const float* w2    = (const float*)d_in[5];
  const float* b2    = (const float*)d_in[6];
  const float* w3    = (const float*)d_in[7];
  const float* b3    = (const float*)d_in[8];
  float* out = (float*)d_out;

  const size_t sh = (size_t)64 * NE * 2 * 2    // dtA + dtB  32768
                  + (size_t)32 * NE * 2;       // qtile       8192  -> 40960 exactly
  hipFuncSetAttribute((const void*)knrm_part,
                      hipFuncAttributeMaxDynamicSharedMemorySize, (int)sh);

  norm_kernel<<<dim3(VOCAB / 8), dim3(256), 0, stream>>>(emb);
  knrm_part<<<dim3(NB * 2), dim3(512), sh, stream>>>(query, doc);
  knrm_finish<<<dim3(NB), dim3(640), 0, stream>>>(w1, b1, w2, b2, w3, b3, out);
}